// Round 10
// baseline (163.171 us; speedup 1.0000x reference)
//
#include <hip/hip_runtime.h>
#include <stdint.h>

typedef short bf16x8 __attribute__((ext_vector_type(8)));
typedef float f32x4 __attribute__((ext_vector_type(4)));
typedef unsigned short u16;
typedef unsigned short u16x4 __attribute__((ext_vector_type(4)));
typedef unsigned int u32;
typedef unsigned int u32x4 __attribute__((ext_vector_type(4)));
typedef unsigned long long u64;

// B=16, N=1024, T=6, V=32000, D=128, F=64, H=4, LC=400

__device__ inline u16 f2b(float f) {
    unsigned u = __float_as_uint(f);
    u += 0x7fffu + ((u >> 16) & 1u);
    return (u16)(u >> 16);
}

__device__ inline float wred_sum(float v) {
    #pragma unroll
    for (int m = 32; m >= 1; m >>= 1) v += __shfl_xor(v, m, 64);
    return v;
}

// ---------------------------------------------------------------------------
// K_pre mega-kernel.
//  blocks [0,1024):    adj -> bitmask (float4 loads, shfl word-assembly),
//                      diagonal fix, per-row deg0 flag.
//  blocks [1024,3072): x0 = sum_t emb[story] + (valid ? dh : 0)  (float4)
//  blocks [3072,3752): pack W1/W2/W3 -> MFMA B-fragments, 17 col-tiles/kt
__global__ __launch_bounds__(256) void k_pre(const float* __restrict__ adj,
                                             const int* __restrict__ kb,
                                             const int* __restrict__ cv,
                                             const int* __restrict__ story,
                                             const float* __restrict__ dh,
                                             const float* __restrict__ emb,
                                             const float* __restrict__ W1,
                                             const float* __restrict__ a1,
                                             const float* __restrict__ W2,
                                             const float* __restrict__ a2,
                                             const float* __restrict__ W3,
                                             const float* __restrict__ a3,
                                             u64* __restrict__ mask,
                                             u16* __restrict__ x0,
                                             u16* __restrict__ Bp1,
                                             u16* __restrict__ Bp2,
                                             u16* __restrict__ Bp3,
                                             float* __restrict__ d0g) {
    int bid = blockIdx.x;
    int tid = threadIdx.x;
    if (bid < 1024) {
        int w = tid >> 6, l = tid & 63;
        int rbase = (bid << 4) + (w << 2);
        int b = rbase >> 10;
        int start = kb[b] + cv[b];
        const float4* a4 = (const float4*)adj;
        for (int r = 0; r < 4; ++r) {
            int row = rbase + r;
            int i = row & 1023;
            u32 m16 = 0;
            #pragma unroll
            for (int q = 0; q < 4; ++q) {
                float4 v = a4[(size_t)row * 256 + (l << 2) + q];
                m16 |= (u32)(v.x > 0.0f) << (q * 4);
                m16 |= (u32)(v.y > 0.0f) << (q * 4 + 1);
                m16 |= (u32)(v.z > 0.0f) << (q * 4 + 2);
                m16 |= (u32)(v.w > 0.0f) << (q * 4 + 3);
            }
            if (i >= start && (i >> 4) == l) m16 |= 1u << (i & 15);
            u64 bal = __ballot(m16 != 0);
            u32 s0 = (u32)__shfl((int)m16, (l << 2) + 0, 64);
            u32 s1 = (u32)__shfl((int)m16, (l << 2) + 1, 64);
            u32 s2 = (u32)__shfl((int)m16, (l << 2) + 2, 64);
            u32 s3 = (u32)__shfl((int)m16, (l << 2) + 3, 64);
            if (l < 16) {
                u64 word = (u64)(s0 | (s1 << 16)) | ((u64)(s2 | (s3 << 16)) << 32);
                mask[((size_t)row << 4) + l] = word;
            }
            if (l == 0) d0g[row] = (bal == 0ull) ? 1.0f : 0.0f;
        }
    } else if (bid < 3072) {
        int w = tid >> 6, l = tid & 63;
        int r = l >> 5, dq = l & 31;
        int bn = ((bid - 1024) << 3) + (w << 1) + r;
        int b = bn >> 10, n = bn & 1023;
        const int* st = story + (size_t)bn * 6;
        const float4* emb4 = (const float4*)emb;
        float4 acc = {0.f, 0.f, 0.f, 0.f};
        #pragma unroll
        for (int t = 0; t < 6; ++t) {
            int tok = st[t];
            float4 e = emb4[(size_t)tok * 32 + dq];
            acc.x += e.x; acc.y += e.y; acc.z += e.z; acc.w += e.w;
        }
        int off = n - (kb[b] - 1);
        if (off >= 0 && off < cv[b]) {
            float4 d = ((const float4*)dh)[((size_t)b * 400 + off) * 32 + dq];
            acc.x += d.x; acc.y += d.y; acc.z += d.z; acc.w += d.w;
        }
        u16x4 pk = {f2b(acc.x), f2b(acc.y), f2b(acc.z), f2b(acc.w)};
        *(u16x4*)(x0 + ((size_t)bn << 7) + (dq << 2)) = pk;
    } else {
        int pb = bid - 3072;
        const float *W, *a; u16* Bp; int K;
        if (pb < 136)      { W = W1; a = a1; Bp = Bp1; K = 128; }
        else if (pb < 408) { W = W2; a = a2; Bp = Bp2; K = 256; pb -= 136; }
        else               { W = W3; a = a3; Bp = Bp3; K = 256; pb -= 408; }
        int id = pb * 256 + tid;
        int j = id & 7, lane = (id >> 3) & 63, fr = id >> 9;
        int kt = fr / 17, ct = fr - kt * 17;
        int kk = (kt << 5) + ((lane >> 4) << 3) + j;
        u16 o;
        if (ct < 16) {
            int col = (ct << 4) | (lane & 15);
            o = f2b(W[((size_t)(col >> 6) * K + kk) * 64 + (col & 63)]);
        } else {
            int c = lane & 15;
            if (c < 8) {
                int h = c >> 1, wh = c & 1;
                const float4* wr = (const float4*)(W + ((size_t)h * K + kk) * 64);
                const float4* av = (const float4*)(a + h * 128 + wh * 64);
                float s = 0.0f;
                #pragma unroll
                for (int q = 0; q < 16; ++q) {
                    float4 x = wr[q], y = av[q];
                    s += x.x * y.x + x.y * y.y + x.z * y.z + x.w * y.w;
                }
                o = f2b(s);
            } else o = 0;
        }
        Bp[id] = o;
    }
}

// ---------------------------------------------------------------------------
// K_gemm: Wh = A @ Wcat (bf16 MFMA). Block = one 16-row tile, 4 waves = 4
// col-quarters (heads). 1024 blocks -> 4096 waves (4/SIMD). Wave-private
// LDS transpose (no barrier). f1/f2 from 17th col-tile on colq==0.
template <int KT>
__global__ __launch_bounds__(256) void k_gemm(const u16* __restrict__ A,
                                              const u16* __restrict__ Bp,
                                              u16* __restrict__ WhB,
                                              float* __restrict__ f1,
                                              float* __restrict__ f2) {
    constexpr int K = KT * 32;
    __shared__ __align__(16) u16 tile[4][1024];   // [wave][col2*16 + row]
    int tid = threadIdx.x, w = tid >> 6, l = tid & 63;
    int colq = w;
    int m0 = blockIdx.x << 4;
    int b = m0 >> 10, n0 = m0 & 1023;
    int jt = n0 >> 5, halfsel = (n0 >> 4) & 1;
    const bf16x8* Av = (const bf16x8*)A;
    const bf16x8* Bv = (const bf16x8*)Bp;
    int arow = m0 + (l & 15);
    bf16x8 af[KT];
    #pragma unroll
    for (int kt = 0; kt < KT; ++kt)
        af[kt] = Av[((size_t)arow * K + (kt << 5) + ((l >> 4) << 3)) >> 3];
    f32x4 acc[4];
    #pragma unroll
    for (int c = 0; c < 4; ++c) acc[c] = f32x4{0.f, 0.f, 0.f, 0.f};
    f32x4 acc16 = {0.f, 0.f, 0.f, 0.f};
    #pragma unroll
    for (int kt = 0; kt < KT; ++kt) {
        #pragma unroll
        for (int c = 0; c < 4; ++c) {
            bf16x8 bv = Bv[(size_t)(kt * 17 + (colq << 2) + c) * 64 + l];
            acc[c] = __builtin_amdgcn_mfma_f32_16x16x32_bf16(af[kt], bv, acc[c], 0, 0, 0);
        }
        if (colq == 0)
            acc16 = __builtin_amdgcn_mfma_f32_16x16x32_bf16(
                af[kt], Bv[(size_t)(kt * 17 + 16) * 64 + l], acc16, 0, 0, 0);
    }
    int co = l & 15, ro = (l >> 4) << 2;
    if (colq == 0 && co < 8) {
        int hh = co >> 1;
        float* fp = (co & 1) ? f2 : f1;
        int base = (((b << 2) + hh) << 10) + n0 + ro;
        #pragma unroll
        for (int r = 0; r < 4; ++r) fp[base + r] = acc16[r];
    }
    u16* tw = tile[w];
    #pragma unroll
    for (int c = 0; c < 4; ++c) {
        int col2 = (c << 4) + co;
        u16x4 pk;
        #pragma unroll
        for (int r = 0; r < 4; ++r) pk[r] = f2b(acc[c][r]);
        *(u16x4*)(tw + (col2 << 4) + ro) = pk;
    }
    // wave-private tile: in-wave lgkmcnt ordering suffices, no __syncthreads
    int bh = (b << 2) + colq;
    int lp = (halfsel << 5) + (l & 31);
    #pragma unroll
    for (int ftq = 0; ftq < 2; ++ftq) {
        int ft = (ftq << 1) + (l >> 5);
        int col2 = (ft << 4) + (l & 15);
        int r0 = ((l >> 4) & 1) << 3;
        bf16x8 v = *(const bf16x8*)(tw + (col2 << 4) + r0);
        size_t fidx = (size_t)((bh << 7) + (jt << 2) + ft);
        *(bf16x8*)(WhB + (fidx * 64 + lp) * 8) = v;
    }
}

// ---------------------------------------------------------------------------
// PV core: P generated in registers (log2 domain, no max-shift), inline
// v_exp, row sums via ones-column MFMA. 2 LDS b128 reads / jt.
#define PV_CORE(f2v4, mw, f1i, d0f, fragbase, Bv, acc, accs, g)                  \
    {                                                                            \
        u32 onep = ((l & 15) == 0) ? 0x3F803F80u : 0u;                           \
        u32x4 ov = {onep, onep, onep, onep};                                     \
        bf16x8 sfrag = __builtin_bit_cast(bf16x8, ov);                           \
        for (int jt = 0; jt < 32; ++jt) {                                        \
            u32 sh = mw[jt] >> (g << 3);                                         \
            f32x4 fa = f2v4[(jt << 3) + (g << 1)];                               \
            f32x4 fb = f2v4[(jt << 3) + (g << 1) + 1];                           \
            float p[8];                                                          \
            _Pragma("unroll")                                                    \
            for (int jj = 0; jj < 8; ++jj) {                                     \
                float f2j = (jj < 4) ? fa[jj] : fb[jj - 4];                      \
                float t = f1i + f2j;                                             \
                float e = fmaxf(t, 0.2f * t);                                    \
                float ex;                                                        \
                asm("v_exp_f32 %0, %1" : "=v"(ex) : "v"(e));                     \
                p[jj] = (sh & (1u << jj)) ? ex : d0f;                            \
            }                                                                    \
            u32x4 pk;                                                            \
            _Pragma("unroll")                                                    \
            for (int q = 0; q < 4; ++q) {                                        \
                u32 r;                                                           \
                asm("v_cvt_pk_bf16_f32 %0, %1, %2"                               \
                    : "=v"(r) : "v"(p[2 * q]), "v"(p[2 * q + 1]));               \
                pk[q] = r;                                                       \
            }                                                                    \
            bf16x8 af = __builtin_bit_cast(bf16x8, pk);                          \
            accs = __builtin_amdgcn_mfma_f32_16x16x32_bf16(af, sfrag, accs, 0, 0, 0); \
            _Pragma("unroll")                                                    \
            for (int ft = 0; ft < 4; ++ft)                                       \
                acc[ft] = __builtin_amdgcn_mfma_f32_16x16x32_bf16(               \
                    af, Bv[(size_t)(fragbase + (jt << 2) + ft) * 64 + l], acc[ft], 0, 0, 0); \
        }                                                                        \
    }

// ---------------------------------------------------------------------------
// K_pv: 256 blocks x 1024 threads. Block = (bh, quarter): 16 waves, ALL on one
// CU, ALL reading the same WhB panel -> L1 serves repeat fragment reads.
// One wave = one 16-row i-tile. MODE 0: concat (elu->bf16). MODE 1: fp32 out3.
template <int MODE>
__global__ __launch_bounds__(1024) void k_pv(const u32* __restrict__ mask32,
                                             const float* __restrict__ f1g,
                                             const float* __restrict__ f2g,
                                             const float* __restrict__ d0g,
                                             const bf16x8* __restrict__ Bv,
                                             u16* __restrict__ xout,
                                             float* __restrict__ out3) {
    __shared__ __align__(16) float f2s[1024];
    const float LOG2E = 1.44269504088896340736f;
    int tid = threadIdx.x;
    int w = tid >> 6, l = tid & 63;
    int bh = blockIdx.x >> 2;
    int b = bh >> 2, h = bh & 3;
    int itile = ((blockIdx.x & 3) << 4) + w;
    int i0 = itile << 4;
    f2s[tid] = f2g[(bh << 10) + tid] * LOG2E;
    __syncthreads();
    int row = l & 15, g = l >> 4;
    int i = i0 + row;
    float f1i = f1g[(bh << 10) + i] * LOG2E;
    float d0f = d0g[(b << 10) + i];
    const u32x4* m4 = (const u32x4*)(mask32 + (((size_t)(b << 10) + i) << 5));
    u32 mw[32];
    #pragma unroll
    for (int t4 = 0; t4 < 8; ++t4) {
        u32x4 q = m4[t4];
        mw[t4 * 4 + 0] = q[0]; mw[t4 * 4 + 1] = q[1];
        mw[t4 * 4 + 2] = q[2]; mw[t4 * 4 + 3] = q[3];
    }
    f32x4 acc[4];
    #pragma unroll
    for (int ft = 0; ft < 4; ++ft) acc[ft] = f32x4{0.f, 0.f, 0.f, 0.f};
    f32x4 accs = {0.f, 0.f, 0.f, 0.f};
    const f32x4* f2v4 = (const f32x4*)f2s;
    int fragbase = bh << 7;
    PV_CORE(f2v4, mw, f1i, d0f, fragbase, Bv, acc, accs, g)
    #pragma unroll
    for (int reg = 0; reg < 4; ++reg) {
        int orow = (g << 2) + reg;
        float s = __shfl(accs[reg], g << 4, 64);
        float rinv = 1.0f / s;
        int grow = i0 + orow;
        #pragma unroll
        for (int ft = 0; ft < 4; ++ft) {
            float v = acc[ft][reg] * rinv;
            if (MODE == 0) {
                float e2 = v > 0.0f ? v : (__expf(v) - 1.0f);   // elu
                xout[((size_t)((b << 10) + grow) << 8) + (h << 6) + (ft << 4) + row] = f2b(e2);
            } else {
                out3[((size_t)((bh << 10) + grow) << 6) + (ft << 4) + row] = v;
            }
        }
    }
}

// ---------------------------------------------------------------------------
// K_final: head-mean -> sigmoid -> dot(hidden) -> outputs. 4096 blocks x 4 waves.
__global__ __launch_bounds__(256) void k_final(const float* __restrict__ out3,
                                               const float* __restrict__ hidden,
                                               float* __restrict__ dout) {
    int tid = threadIdx.x, w = tid >> 6, f = tid & 63;
    int bn = blockIdx.x * 4 + w;
    int b = bn >> 10, n = bn & 1023;
    float s = 0.0f;
    #pragma unroll
    for (int h = 0; h < 4; ++h)
        s += out3[((size_t)((((b << 2) + h) << 10) + n) << 6) + f];
    s *= 0.25f;
    float x = 1.0f / (1.0f + __expf(-s));
    float hid = hidden[(b << 6) + f];
    float logit = wred_sum(x * hid);
    if (f == 0) {
        dout[bn] = 1.0f / (1.0f + __expf(-logit));
        dout[17408 + bn] = logit;
    }
    if (n == 0) dout[16384 + (b << 6) + f] = hid;
}

// ---------------------------------------------------------------------------
extern "C" void kernel_launch(void* const* d_in, const int* in_sizes, int n_in,
                              void* d_out, int out_size, void* d_ws, size_t ws_size,
                              hipStream_t stream) {
    const int*   story  = (const int*)d_in[0];
    const int*   kb     = (const int*)d_in[1];
    const int*   cv     = (const int*)d_in[2];
    const float* hidden = (const float*)d_in[3];
    const float* dh     = (const float*)d_in[4];
    const float* adj    = (const float*)d_in[5];
    const float* emb    = (const float*)d_in[6];
    const float* W1     = (const float*)d_in[7];
    const float* a1     = (const float*)d_in[8];
    const float* W2     = (const float*)d_in[9];
    const float* a2     = (const float*)d_in[10];
    const float* W3     = (const float*)d_in[11];
    const float* a3     = (const float*)d_in[12];
    float* dout = (float*)d_out;

    char* ws = (char*)d_ws;
    u64*   mask   = (u64*)(ws + 0);               //  2 MB
    u32*   mask32 = (u32*)(ws + 0);               //  alias
    u16*   x0   = (u16*)(ws + 2097152);           //  4 MB
    u16*   xbf  = (u16*)(ws + 6291456);           //  8 MB
    u16*   WhB  = (u16*)(ws + 14680064);          //  8 MB packed B-fragments
    float* f1   = (float*)(ws + 23068672);        //  256 KB
    float* f2   = (float*)(ws + 23330816);        //  256 KB
    u16*   Bp1  = (u16*)(ws + 23592960);          //  68 KB
    u16*   Bp2  = (u16*)(ws + 23662592);          //  136 KB
    u16*   Bp3  = (u16*)(ws + 23801856);          //  136 KB
    float* d0g  = (float*)(ws + 23941120);        //  64 KB
    float* out3 = (float*)(ws + 25165824);        //  16 MB (end ~41 MB)

    k_pre<<<3752, 256, 0, stream>>>(adj, kb, cv, story, dh, emb,
                                    W1, a1, W2, a2, W3, a3,
                                    mask, x0, Bp1, Bp2, Bp3, d0g);

    // ---- layer 1 (K=128) ----
    k_gemm<4><<<1024, 256, 0, stream>>>(x0, Bp1, WhB, f1, f2);
    k_pv<0><<<256, 1024, 0, stream>>>(mask32, f1, f2, d0g, (const bf16x8*)WhB, xbf, nullptr);

    // ---- layer 2 (K=256) ----
    k_gemm<8><<<1024, 256, 0, stream>>>(xbf, Bp2, WhB, f1, f2);
    k_pv<0><<<256, 1024, 0, stream>>>(mask32, f1, f2, d0g, (const bf16x8*)WhB, xbf, nullptr);

    // ---- layer 3 (K=256) ----
    k_gemm<8><<<1024, 256, 0, stream>>>(xbf, Bp3, WhB, f1, f2);
    k_pv<1><<<256, 1024, 0, stream>>>(mask32, f1, f2, d0g, (const bf16x8*)WhB, nullptr, out3);

    k_final<<<4096, 256, 0, stream>>>(out3, hidden, dout);
}

// Round 11
// 143.917 us; speedup vs baseline: 1.1338x; 1.1338x over previous
//
#include <hip/hip_runtime.h>
#include <stdint.h>

typedef short bf16x8 __attribute__((ext_vector_type(8)));
typedef float f32x4 __attribute__((ext_vector_type(4)));
typedef unsigned short u16;
typedef unsigned short u16x4 __attribute__((ext_vector_type(4)));
typedef unsigned int u32;
typedef unsigned int u32x4 __attribute__((ext_vector_type(4)));
typedef unsigned long long u64;

// B=16, N=1024, T=6, V=32000, D=128, F=64, H=4, LC=400

__device__ inline u16 f2b(float f) {
    unsigned u = __float_as_uint(f);
    u += 0x7fffu + ((u >> 16) & 1u);
    return (u16)(u >> 16);
}

__device__ inline float wred_sum(float v) {
    #pragma unroll
    for (int m = 32; m >= 1; m >>= 1) v += __shfl_xor(v, m, 64);
    return v;
}

// ---------------------------------------------------------------------------
// K_pre mega-kernel (R7 version, measured fast).
__global__ __launch_bounds__(256) void k_pre(const float* __restrict__ adj,
                                             const int* __restrict__ kb,
                                             const int* __restrict__ cv,
                                             const int* __restrict__ story,
                                             const float* __restrict__ dh,
                                             const float* __restrict__ emb,
                                             const float* __restrict__ W1,
                                             const float* __restrict__ a1,
                                             const float* __restrict__ W2,
                                             const float* __restrict__ a2,
                                             const float* __restrict__ W3,
                                             const float* __restrict__ a3,
                                             u64* __restrict__ mask,
                                             u16* __restrict__ x0,
                                             u16* __restrict__ Bp1,
                                             u16* __restrict__ Bp2,
                                             u16* __restrict__ Bp3,
                                             float* __restrict__ d0g) {
    int bid = blockIdx.x;
    int tid = threadIdx.x;
    if (bid < 1024) {
        int w = tid >> 6, l = tid & 63;
        int rbase = (bid << 4) + (w << 2);
        int b = rbase >> 10;
        int start = kb[b] + cv[b];
        const float4* a4 = (const float4*)adj;
        for (int r = 0; r < 4; ++r) {
            int row = rbase + r;
            int i = row & 1023;
            u32 m16 = 0;
            #pragma unroll
            for (int q = 0; q < 4; ++q) {
                float4 v = a4[(size_t)row * 256 + (l << 2) + q];
                m16 |= (u32)(v.x > 0.0f) << (q * 4);
                m16 |= (u32)(v.y > 0.0f) << (q * 4 + 1);
                m16 |= (u32)(v.z > 0.0f) << (q * 4 + 2);
                m16 |= (u32)(v.w > 0.0f) << (q * 4 + 3);
            }
            if (i >= start && (i >> 4) == l) m16 |= 1u << (i & 15);
            u64 bal = __ballot(m16 != 0);
            u32 s0 = (u32)__shfl((int)m16, (l << 2) + 0, 64);
            u32 s1 = (u32)__shfl((int)m16, (l << 2) + 1, 64);
            u32 s2 = (u32)__shfl((int)m16, (l << 2) + 2, 64);
            u32 s3 = (u32)__shfl((int)m16, (l << 2) + 3, 64);
            if (l < 16) {
                u64 word = (u64)(s0 | (s1 << 16)) | ((u64)(s2 | (s3 << 16)) << 32);
                mask[((size_t)row << 4) + l] = word;
            }
            if (l == 0) d0g[row] = (bal == 0ull) ? 1.0f : 0.0f;
        }
    } else if (bid < 3072) {
        int w = tid >> 6, l = tid & 63;
        int r = l >> 5, dq = l & 31;
        int bn = ((bid - 1024) << 3) + (w << 1) + r;
        int b = bn >> 10, n = bn & 1023;
        const int* st = story + (size_t)bn * 6;
        const float4* emb4 = (const float4*)emb;
        float4 acc = {0.f, 0.f, 0.f, 0.f};
        #pragma unroll
        for (int t = 0; t < 6; ++t) {
            int tok = st[t];
            float4 e = emb4[(size_t)tok * 32 + dq];
            acc.x += e.x; acc.y += e.y; acc.z += e.z; acc.w += e.w;
        }
        int off = n - (kb[b] - 1);
        if (off >= 0 && off < cv[b]) {
            float4 d = ((const float4*)dh)[((size_t)b * 400 + off) * 32 + dq];
            acc.x += d.x; acc.y += d.y; acc.z += d.z; acc.w += d.w;
        }
        u16x4 pk = {f2b(acc.x), f2b(acc.y), f2b(acc.z), f2b(acc.w)};
        *(u16x4*)(x0 + ((size_t)bn << 7) + (dq << 2)) = pk;
    } else {
        int pb = bid - 3072;
        const float *W, *a; u16* Bp; int K;
        if (pb < 136)      { W = W1; a = a1; Bp = Bp1; K = 128; }
        else if (pb < 408) { W = W2; a = a2; Bp = Bp2; K = 256; pb -= 136; }
        else               { W = W3; a = a3; Bp = Bp3; K = 256; pb -= 408; }
        int id = pb * 256 + tid;
        int j = id & 7, lane = (id >> 3) & 63, fr = id >> 9;
        int kt = fr / 17, ct = fr - kt * 17;
        int kk = (kt << 5) + ((lane >> 4) << 3) + j;
        u16 o;
        if (ct < 16) {
            int col = (ct << 4) | (lane & 15);
            o = f2b(W[((size_t)(col >> 6) * K + kk) * 64 + (col & 63)]);
        } else {
            int c = lane & 15;
            if (c < 8) {
                int h = c >> 1, wh = c & 1;
                const float4* wr = (const float4*)(W + ((size_t)h * K + kk) * 64);
                const float4* av = (const float4*)(a + h * 128 + wh * 64);
                float s = 0.0f;
                #pragma unroll
                for (int q = 0; q < 16; ++q) {
                    float4 x = wr[q], y = av[q];
                    s += x.x * y.x + x.y * y.y + x.z * y.z + x.w * y.w;
                }
                o = f2b(s);
            } else o = 0;
        }
        Bp[id] = o;
    }
}

// ---------------------------------------------------------------------------
// K_gemm (R7 version: 512 blocks, fragment reuse across 2 row-tiles).
template <int KT>
__global__ __launch_bounds__(256) void k_gemm(const u16* __restrict__ A,
                                              const u16* __restrict__ Bp,
                                              u16* __restrict__ WhB,
                                              float* __restrict__ f1,
                                              float* __restrict__ f2) {
    constexpr int K = KT * 32;
    __shared__ __align__(16) u16 tile[4][2][2048];   // [wave][tile][col2*16+row]
    int tid = threadIdx.x, w = tid >> 6, l = tid & 63;
    int rtp = blockIdx.x;
    int colq = w;
    int m0 = rtp << 5;
    int b = m0 >> 10, n0 = m0 & 1023;
    int jt = n0 >> 5;
    const bf16x8* Av = (const bf16x8*)A;
    const bf16x8* Bv = (const bf16x8*)Bp;
    int arowA = m0 + (l & 15);
    bf16x8 afA[KT], afB[KT];
    #pragma unroll
    for (int kt = 0; kt < KT; ++kt) {
        size_t base = ((size_t)arowA * K + (kt << 5) + ((l >> 4) << 3)) >> 3;
        afA[kt] = Av[base];
        afB[kt] = Av[base + ((16 * K) >> 3)];
    }
    f32x4 accA[4], accB[4];
    #pragma unroll
    for (int c = 0; c < 4; ++c) { accA[c] = f32x4{0.f,0.f,0.f,0.f}; accB[c] = f32x4{0.f,0.f,0.f,0.f}; }
    f32x4 acc16A = {0.f,0.f,0.f,0.f}, acc16B = {0.f,0.f,0.f,0.f};
    #pragma unroll
    for (int kt = 0; kt < KT; ++kt) {
        #pragma unroll
        for (int c = 0; c < 4; ++c) {
            bf16x8 bv = Bv[(size_t)(kt * 17 + (colq << 2) + c) * 64 + l];
            accA[c] = __builtin_amdgcn_mfma_f32_16x16x32_bf16(afA[kt], bv, accA[c], 0, 0, 0);
            accB[c] = __builtin_amdgcn_mfma_f32_16x16x32_bf16(afB[kt], bv, accB[c], 0, 0, 0);
        }
        if (colq == 0) {
            bf16x8 bv = Bv[(size_t)(kt * 17 + 16) * 64 + l];
            acc16A = __builtin_amdgcn_mfma_f32_16x16x32_bf16(afA[kt], bv, acc16A, 0, 0, 0);
            acc16B = __builtin_amdgcn_mfma_f32_16x16x32_bf16(afB[kt], bv, acc16B, 0, 0, 0);
        }
    }
    int co = l & 15, ro = (l >> 4) << 2;
    if (colq == 0 && co < 8) {
        int hh = co >> 1;
        float* fp = (co & 1) ? f2 : f1;
        int base = (((b << 2) + hh) << 10) + n0 + ro;
        #pragma unroll
        for (int r = 0; r < 4; ++r) {
            fp[base + r] = acc16A[r];
            fp[base + 16 + r] = acc16B[r];
        }
    }
    u16* twA = tile[w][0]; u16* twB = tile[w][1];
    #pragma unroll
    for (int c = 0; c < 4; ++c) {
        int col2 = (c << 4) + co;
        u16x4 pkA, pkB;
        #pragma unroll
        for (int r = 0; r < 4; ++r) { pkA[r] = f2b(accA[c][r]); pkB[r] = f2b(accB[c][r]); }
        *(u16x4*)(twA + (col2 << 4) + ro) = pkA;
        *(u16x4*)(twB + (col2 << 4) + ro) = pkB;
    }
    __syncthreads();
    int bh = (b << 2) + colq;
    int lq = l & 31;
    #pragma unroll
    for (int ftq = 0; ftq < 2; ++ftq) {
        int ft = (ftq << 1) + (l >> 5);
        int col2 = (ft << 4) + (l & 15);
        int r0 = ((l >> 4) & 1) << 3;
        bf16x8 vA = *(const bf16x8*)(twA + (col2 << 4) + r0);
        bf16x8 vB = *(const bf16x8*)(twB + (col2 << 4) + r0);
        size_t fidx = (size_t)((bh << 7) + (jt << 2) + ft);
        *(bf16x8*)(WhB + (fidx * 64 + lq) * 8) = vA;
        *(bf16x8*)(WhB + (fidx * 64 + 32 + lq) * 8) = vB;
    }
}

// ---------------------------------------------------------------------------
// PV core macro (R7-proven, 32-jt, used by pv3): inline v_exp, ones-col MFMA.
#define PV_CORE(f2v4, mw, f1i, d0f, fragbase, Bv, acc, accs, g)                  \
    {                                                                            \
        u32 onep = ((l & 15) == 0) ? 0x3F803F80u : 0u;                           \
        u32x4 ov = {onep, onep, onep, onep};                                     \
        bf16x8 sfrag = __builtin_bit_cast(bf16x8, ov);                           \
        for (int jt = 0; jt < 32; ++jt) {                                        \
            u32 sh = mw[jt] >> (g << 3);                                         \
            f32x4 fa = f2v4[(jt << 3) + (g << 1)];                               \
            f32x4 fb = f2v4[(jt << 3) + (g << 1) + 1];                           \
            float p[8];                                                          \
            _Pragma("unroll")                                                    \
            for (int jj = 0; jj < 8; ++jj) {                                     \
                float f2j = (jj < 4) ? fa[jj] : fb[jj - 4];                      \
                float t = f1i + f2j;                                             \
                float e = fmaxf(t, 0.2f * t);                                    \
                float ex;                                                        \
                asm("v_exp_f32 %0, %1" : "=v"(ex) : "v"(e));                     \
                p[jj] = (sh & (1u << jj)) ? ex : d0f;                            \
            }                                                                    \
            u32x4 pk;                                                            \
            _Pragma("unroll")                                                    \
            for (int q = 0; q < 4; ++q) {                                        \
                u32 r;                                                           \
                asm("v_cvt_pk_bf16_f32 %0, %1, %2"                               \
                    : "=v"(r) : "v"(p[2 * q]), "v"(p[2 * q + 1]));               \
                pk[q] = r;                                                       \
            }                                                                    \
            bf16x8 af = __builtin_bit_cast(bf16x8, pk);                          \
            accs = __builtin_amdgcn_mfma_f32_16x16x32_bf16(af, sfrag, accs, 0, 0, 0); \
            _Pragma("unroll")                                                    \
            for (int ft = 0; ft < 4; ++ft)                                       \
                acc[ft] = __builtin_amdgcn_mfma_f32_16x16x32_bf16(               \
                    af, Bv[(size_t)(fragbase + (jt << 2) + ft) * 64 + l], acc[ft], 0, 0, 0); \
        }                                                                        \
    }

// ---------------------------------------------------------------------------
// K_pv0: concat layers, jt-split for 8 waves/SIMD.
// 2048 blocks x 256 thr (8 blocks/CU). Block = (bh, itile-pair).
// Wave w: itile = pair*2 + (w>>1), jhalf = w&1 (16 of 32 jt-tiles each).
// Partial acc combined via LDS; jhalf==0 wave runs the epilogue.
__global__ __launch_bounds__(256, 8) void k_pv0(const u32* __restrict__ mask32,
                                                const float* __restrict__ f1g,
                                                const float* __restrict__ f2g,
                                                const float* __restrict__ d0g,
                                                const bf16x8* __restrict__ Bv,
                                                u16* __restrict__ xout) {
    __shared__ __align__(16) float f2s[1024];
    __shared__ float comb[2][20][64];   // [itile slot][value][lane]
    const float LOG2E = 1.44269504088896340736f;
    int tid = threadIdx.x;
    int w = tid >> 6, l = tid & 63;
    int bh = blockIdx.x >> 5;
    int b = bh >> 2, h = bh & 3;
    int slot = w >> 1, jh = w & 1;
    int itile = ((blockIdx.x & 31) << 1) + slot;
    int i0 = itile << 4;
    for (int idx = tid; idx < 1024; idx += 256) f2s[idx] = f2g[(bh << 10) + idx] * LOG2E;
    __syncthreads();
    int row = l & 15, g = l >> 4;
    int i = i0 + row;
    float f1i = f1g[(bh << 10) + i] * LOG2E;
    float d0f = d0g[(b << 10) + i];
    const u32x4* m4 = (const u32x4*)(mask32 + (((size_t)(b << 10) + i) << 5)) + (jh << 2);
    f32x4 acc[4];
    #pragma unroll
    for (int ft = 0; ft < 4; ++ft) acc[ft] = f32x4{0.f, 0.f, 0.f, 0.f};
    f32x4 accs = {0.f, 0.f, 0.f, 0.f};
    const f32x4* f2v4 = (const f32x4*)f2s;
    int fragbase = bh << 7;
    {
        u32 onep = (row == 0) ? 0x3F803F80u : 0u;
        u32x4 ov = {onep, onep, onep, onep};
        bf16x8 sfrag = __builtin_bit_cast(bf16x8, ov);
        u32x4 mwq;
        for (int t = 0; t < 16; ++t) {
            if ((t & 3) == 0) mwq = m4[t >> 2];
            int jtg = (jh << 4) + t;
            u32 sh = mwq[t & 3] >> (g << 3);
            f32x4 fa = f2v4[(jtg << 3) + (g << 1)];
            f32x4 fb = f2v4[(jtg << 3) + (g << 1) + 1];
            float p[8];
            #pragma unroll
            for (int jj = 0; jj < 8; ++jj) {
                float f2j = (jj < 4) ? fa[jj] : fb[jj - 4];
                float tt = f1i + f2j;
                float e = fmaxf(tt, 0.2f * tt);
                float ex;
                asm("v_exp_f32 %0, %1" : "=v"(ex) : "v"(e));
                p[jj] = (sh & (1u << jj)) ? ex : d0f;
            }
            u32x4 pk;
            #pragma unroll
            for (int q = 0; q < 4; ++q) {
                u32 r;
                asm("v_cvt_pk_bf16_f32 %0, %1, %2"
                    : "=v"(r) : "v"(p[2 * q]), "v"(p[2 * q + 1]));
                pk[q] = r;
            }
            bf16x8 af = __builtin_bit_cast(bf16x8, pk);
            accs = __builtin_amdgcn_mfma_f32_16x16x32_bf16(af, sfrag, accs, 0, 0, 0);
            #pragma unroll
            for (int ft = 0; ft < 4; ++ft)
                acc[ft] = __builtin_amdgcn_mfma_f32_16x16x32_bf16(
                    af, Bv[(size_t)(fragbase + (jtg << 2) + ft) * 64 + l], acc[ft], 0, 0, 0);
        }
    }
    // combine the two jt-halves
    if (jh == 1) {
        #pragma unroll
        for (int v = 0; v < 16; ++v) comb[slot][v][l] = acc[v >> 2][v & 3];
        #pragma unroll
        for (int r = 0; r < 4; ++r) comb[slot][16 + r][l] = accs[r];
    }
    __syncthreads();
    if (jh == 0) {
        #pragma unroll
        for (int v = 0; v < 16; ++v) acc[v >> 2][v & 3] += comb[slot][v][l];
        #pragma unroll
        for (int r = 0; r < 4; ++r) accs[r] += comb[slot][16 + r][l];
        #pragma unroll
        for (int reg = 0; reg < 4; ++reg) {
            int orow = (g << 2) + reg;
            float s = __shfl(accs[reg], g << 4, 64);
            float rinv = 1.0f / s;
            int grow = i0 + orow;
            #pragma unroll
            for (int ft = 0; ft < 4; ++ft) {
                float v = acc[ft][reg] * rinv;
                float e2 = v > 0.0f ? v : (__expf(v) - 1.0f);   // elu
                xout[((size_t)((b << 10) + grow) << 8) + (h << 6) + (ft << 4) + row] = f2b(e2);
            }
        }
    }
}

// ---------------------------------------------------------------------------
// K_pv3 (R7 version): final layer + fused head-mean/sigmoid/hidden-dot.
// Block = (b, itile); wave = head. 1024 blocks. LDS f2 stage -> out reuse.
__global__ __launch_bounds__(256) void k_pv3(const u32* __restrict__ mask32,
                                             const float* __restrict__ f1g,
                                             const float* __restrict__ f2g,
                                             const float* __restrict__ d0g,
                                             const bf16x8* __restrict__ Bv,
                                             const float* __restrict__ hidden,
                                             float* __restrict__ dout) {
    __shared__ __align__(16) float shbuf[4096];   // [h][1024] f2 -> [h][16][64]
    const float LOG2E = 1.44269504088896340736f;
    int tid = threadIdx.x;
    int w = tid >> 6, l = tid & 63;
    int b = blockIdx.x >> 6;
    int itile = blockIdx.x & 63;
    int i0 = itile << 4;
    int bh = (b << 2) + w;
    for (int idx = tid; idx < 4096; idx += 256) shbuf[idx] = f2g[(b << 12) + idx] * LOG2E;
    __syncthreads();
    int row = l & 15, g = l >> 4;
    int i = i0 + row;
    float f1i = f1g[(bh << 10) + i] * LOG2E;
    float d0f = d0g[(b << 10) + i];
    const u32x4* m4 = (const u32x4*)(mask32 + (((size_t)(b << 10) + i) << 5));
    u32 mw[32];
    #pragma unroll
    for (int t4 = 0; t4 < 8; ++t4) {
        u32x4 q = m4[t4];
        mw[t4 * 4 + 0] = q[0]; mw[t4 * 4 + 1] = q[1];
        mw[t4 * 4 + 2] = q[2]; mw[t4 * 4 + 3] = q[3];
    }
    f32x4 acc[4];
    #pragma unroll
    for (int ft = 0; ft < 4; ++ft) acc[ft] = f32x4{0.f, 0.f, 0.f, 0.f};
    f32x4 accs = {0.f, 0.f, 0.f, 0.f};
    const f32x4* f2v4 = (const f32x4*)(shbuf + (w << 10));
    int fragbase = bh << 7;
    PV_CORE(f2v4, mw, f1i, d0f, fragbase, Bv, acc, accs, g)
    __syncthreads();   // all waves done reading f2 -> safe to reuse shbuf
    #pragma unroll
    for (int reg = 0; reg < 4; ++reg) {
        int orow = (g << 2) + reg;
        float s = __shfl(accs[reg], g << 4, 64);
        float rinv = 1.0f / s;
        #pragma unroll
        for (int ft = 0; ft < 4; ++ft)
            shbuf[(w << 10) + (orow << 6) + (ft << 4) + row] = acc[ft][reg] * rinv;
    }
    __syncthreads();
    float hid = hidden[(b << 6) + l];
    #pragma unroll
    for (int k = 0; k < 4; ++k) {
        int rl = (k << 2) + w;
        int o = (rl << 6) + l;
        float s = shbuf[o] + shbuf[1024 + o] + shbuf[2048 + o] + shbuf[3072 + o];
        s *= 0.25f;
        float x = 1.0f / (1.0f + __expf(-s));
        float logit = wred_sum(x * hid);
        if (l == 0) {
            int grow = i0 + rl;
            dout[(b << 10) + grow] = 1.0f / (1.0f + __expf(-logit));
            dout[17408 + (b << 10) + grow] = logit;
        }
    }
    if (itile == 0 && w == 0) dout[16384 + (b << 6) + l] = hid;
}

// ---------------------------------------------------------------------------
extern "C" void kernel_launch(void* const* d_in, const int* in_sizes, int n_in,
                              void* d_out, int out_size, void* d_ws, size_t ws_size,
                              hipStream_t stream) {
    const int*   story  = (const int*)d_in[0];
    const int*   kb     = (const int*)d_in[1];
    const int*   cv     = (const int*)d_in[2];
    const float* hidden = (const float*)d_in[3];
    const float* dh     = (const float*)d_in[4];
    const float* adj    = (const float*)d_in[5];
    const float* emb    = (const float*)d_in[6];
    const float* W1     = (const float*)d_in[7];
    const float* a1     = (const float*)d_in[8];
    const float* W2     = (const float*)d_in[9];
    const float* a2     = (const float*)d_in[10];
    const float* W3     = (const float*)d_in[11];
    const float* a3     = (const float*)d_in[12];
    float* dout = (float*)d_out;

    char* ws = (char*)d_ws;
    u64*   mask   = (u64*)(ws + 0);               //  2 MB
    u32*   mask32 = (u32*)(ws + 0);               //  alias
    u16*   x0   = (u16*)(ws + 2097152);           //  4 MB
    u16*   xbf  = (u16*)(ws + 6291456);           //  8 MB
    u16*   WhB  = (u16*)(ws + 14680064);          //  8 MB packed B-fragments
    float* f1   = (float*)(ws + 23068672);        //  256 KB
    float* f2   = (float*)(ws + 23330816);        //  256 KB
    u16*   Bp1  = (u16*)(ws + 23592960);          //  68 KB
    u16*   Bp2  = (u16*)(ws + 23662592);          //  136 KB
    u16*   Bp3  = (u16*)(ws + 23801856);          //  136 KB
    float* d0g  = (float*)(ws + 23941120);        //  64 KB (end ~23 MB)

    k_pre<<<3752, 256, 0, stream>>>(adj, kb, cv, story, dh, emb,
                                    W1, a1, W2, a2, W3, a3,
                                    mask, x0, Bp1, Bp2, Bp3, d0g);

    // ---- layer 1 (K=128) ----
    k_gemm<4><<<512, 256, 0, stream>>>(x0, Bp1, WhB, f1, f2);
    k_pv0<<<2048, 256, 0, stream>>>(mask32, f1, f2, d0g, (const bf16x8*)WhB, xbf);

    // ---- layer 2 (K=256) ----
    k_gemm<8><<<512, 256, 0, stream>>>(xbf, Bp2, WhB, f1, f2);
    k_pv0<<<2048, 256, 0, stream>>>(mask32, f1, f2, d0g, (const bf16x8*)WhB, xbf);

    // ---- layer 3 (K=256, fused epilogue) ----
    k_gemm<8><<<512, 256, 0, stream>>>(xbf, Bp3, WhB, f1, f2);
    k_pv3<<<1024, 256, 0, stream>>>(mask32, f1, f2, d0g, (const bf16x8*)WhB, hidden, dout);
}